// Round 1
// baseline (439.191 us; speedup 1.0000x reference)
//
#include <hip/hip_runtime.h>
#include <math.h>

// Problem constants (match reference)
#define NPTS      128
#define NEARV     2.0f
#define FARV      6.0f
#define GRID_RES  128
#define CELLV     0.0234375f   /* 3/128, exact in fp32 */

// ---------------------------------------------------------------------------
// Kernel 0: zero the layout flag (d_ws is poisoned with 0xAA before each call)
// ---------------------------------------------------------------------------
__global__ void init_flag_kernel(int* flag) { *flag = 0; }

// ---------------------------------------------------------------------------
// Kernel 1: detect occ_grid storage layout.
// If the harness uploaded the jax bool array raw, elements are 1 byte (0/1);
// reading as u32 then gives words with high bytes set (value > 1) with
// overwhelming probability at 5% occupancy. If it converted to int32, every
// word we read is 0 or 1. We scan elem_count/4 words, which is in-bounds
// under BOTH layouts. flag=1 => byte layout.
// ---------------------------------------------------------------------------
__global__ void detect_layout_kernel(const unsigned int* __restrict__ g,
                                     int nwords, int* __restrict__ flag) {
    int i = blockIdx.x * blockDim.x + threadIdx.x;
    int stride = gridDim.x * blockDim.x;
    int local = 0;
    for (; i < nwords; i += stride)
        if (g[i] > 1u) local = 1;
    if (__any(local) && (threadIdx.x & 63) == 0)
        atomicOr(flag, 1);
}

// ---------------------------------------------------------------------------
// Kernel 2: empty-space-skipping ray march. One thread per ray.
// Bit-exact replication of the reference fori_loop:
//   t_next = t + STEP                    (fp32 add, accumulated)
//   pts    = o + d*t_next                (fp32 mul then fp32 add, NO fma)
//   idx    = (int)((pts - aabb_min)/cell) (fp32 sub, fp32 div, trunc-to-zero)
//   valid  = all(0 <= idx < 128); ic = clip(idx,0,127); occ = grid[ic]
//   hit = active & valid & occ ; past = active & (t_next > far)
// Once a ray goes inactive no state changes => per-thread break is exact.
// ---------------------------------------------------------------------------
__global__ void march_kernel(const float* __restrict__ rays_o,
                             const float* __restrict__ dirs,
                             const void*  __restrict__ grid,
                             const int*   __restrict__ flag,
                             float* __restrict__ eff_near,
                             int n, float step, int max_steps) {
    int r = blockIdx.x * blockDim.x + threadIdx.x;
    if (r >= n) return;

    const bool byte_layout = (*flag != 0);
    const unsigned char* gb = (const unsigned char*)grid;
    const int*           gi = (const int*)grid;

    float ox = rays_o[3 * r + 0], oy = rays_o[3 * r + 1], oz = rays_o[3 * r + 2];
    float dx = dirs[3 * r + 0],   dy = dirs[3 * r + 1],   dz = dirs[3 * r + 2];

    float t  = NEARV;
    float nn = NEARV;

    for (int i = 0; i < max_steps; ++i) {
        float tn = __fadd_rn(t, step);

        float px = __fadd_rn(ox, __fmul_rn(dx, tn));
        float py = __fadd_rn(oy, __fmul_rn(dy, tn));
        float pz = __fadd_rn(oz, __fmul_rn(dz, tn));

        // (p - aabb_min) / cell ; aabb_min = -1.5
        float fx = __fdiv_rn(__fsub_rn(px, -1.5f), CELLV);
        float fy = __fdiv_rn(__fsub_rn(py, -1.5f), CELLV);
        float fz = __fdiv_rn(__fsub_rn(pz, -1.5f), CELLV);

        int ix = (int)fx;   // trunc toward zero == astype(int32)
        int iy = (int)fy;
        int iz = (int)fz;

        bool valid = (ix >= 0) & (ix < GRID_RES) &
                     (iy >= 0) & (iy < GRID_RES) &
                     (iz >= 0) & (iz < GRID_RES);

        bool occ = false;
        if (valid) {
            int cx = min(max(ix, 0), GRID_RES - 1);
            int cy = min(max(iy, 0), GRID_RES - 1);
            int cz = min(max(iz, 0), GRID_RES - 1);
            int lin = (cx << 14) | (cy << 7) | cz;
            occ = byte_layout ? (gb[lin] != 0) : (gi[lin] != 0);
        }

        bool hit  = occ;            // == active & valid & occ (active==true here)
        bool past = tn > FARV;

        if (hit)       nn = fminf(tn, FARV);
        else if (past) nn = FARV;

        if (hit | past) break;      // ray becomes inactive; state frozen
        t = tn;
    }

    eff_near[r] = fminf(nn, FARV);
}

// ---------------------------------------------------------------------------
// Kernel 3: stratified sampling + point generation. One thread per (ray,pt).
//   t_vals = linspace(0,1,128)  (jax sets endpoint exactly -> t[127]=1.0f)
//   z0[i]  = en*(1-t[i]) + 6*t[i]
//   mids   = 0.5*(z0[i]+z0[i+1]); lower/upper per reference
//   z      = lower + (upper-lower)*t_rand
//   pts    = o + d*z
// ---------------------------------------------------------------------------
__device__ __forceinline__ float tval(int i) {
    const float delta = 1.0f / 127.0f;
    return (i >= NPTS - 1) ? 1.0f : __fmul_rn((float)i, delta);
}

__global__ void sample_kernel(const float* __restrict__ rays_o,
                              const float* __restrict__ dirs,
                              const float* __restrict__ t_rand,
                              const float* __restrict__ eff_near,
                              float* __restrict__ out_pts,
                              float* __restrict__ out_z,
                              int n) {
    int gid = blockIdx.x * blockDim.x + threadIdx.x;
    if (gid >= n * NPTS) return;
    int r = gid >> 7;      // ray index
    int p = gid & (NPTS - 1);

    float en = eff_near[r];

    // z0 at p-1, p, p+1
    float tp = tval(p);
    float zp = __fadd_rn(__fmul_rn(en, __fsub_rn(1.0f, tp)), __fmul_rn(FARV, tp));

    float lower, upper;
    if (p == 0) {
        lower = zp;
    } else {
        float tm = tval(p - 1);
        float zm = __fadd_rn(__fmul_rn(en, __fsub_rn(1.0f, tm)), __fmul_rn(FARV, tm));
        lower = __fmul_rn(0.5f, __fadd_rn(zp, zm));   // mids[p-1]
    }
    if (p == NPTS - 1) {
        upper = zp;
    } else {
        float tq = tval(p + 1);
        float zq = __fadd_rn(__fmul_rn(en, __fsub_rn(1.0f, tq)), __fmul_rn(FARV, tq));
        upper = __fmul_rn(0.5f, __fadd_rn(zp, zq));   // mids[p]
    }

    float rr = t_rand[gid];
    float z  = __fadd_rn(lower, __fmul_rn(__fsub_rn(upper, lower), rr));

    out_z[gid] = z;

    float ox = rays_o[3 * r + 0], oy = rays_o[3 * r + 1], oz = rays_o[3 * r + 2];
    float dx = dirs[3 * r + 0],   dy = dirs[3 * r + 1],   dz = dirs[3 * r + 2];

    int b = gid * 3;
    out_pts[b + 0] = __fadd_rn(ox, __fmul_rn(dx, z));
    out_pts[b + 1] = __fadd_rn(oy, __fmul_rn(dy, z));
    out_pts[b + 2] = __fadd_rn(oz, __fmul_rn(dz, z));
}

// ---------------------------------------------------------------------------
extern "C" void kernel_launch(void* const* d_in, const int* in_sizes, int n_in,
                              void* d_out, int out_size, void* d_ws, size_t ws_size,
                              hipStream_t stream) {
    const float* rays_o = (const float*)d_in[0];
    const float* dirs   = (const float*)d_in[1];
    const float* t_rand = (const float*)d_in[2];
    const void*  occ    = d_in[3];

    int n    = in_sizes[0] / 3;    // number of rays
    int nocc = in_sizes[3];        // occ grid element count (128^3)

    float* out     = (float*)d_out;
    float* out_pts = out;                               // n*128*3 floats
    float* out_z   = out + (size_t)n * NPTS * 3;        // n*128 floats

    int*   flag = (int*)d_ws;
    float* eff  = (float*)((char*)d_ws + 256);          // n floats

    // STEP exactly as numpy fp32 computes it: 0.5*||cell||, cell=3/128.
    float cell = CELLV;
    float step = 0.5f * sqrtf(3.0f * (cell * cell));    // host sqrtf: IEEE, matches np
    int max_steps = (int)ceil((6.0 - 2.0) / (double)step) + 2;  // == reference MAX_STEPS

    hipLaunchKernelGGL(init_flag_kernel, dim3(1), dim3(1), 0, stream, flag);
    hipLaunchKernelGGL(detect_layout_kernel, dim3(256), dim3(256), 0, stream,
                       (const unsigned int*)occ, nocc / 4, flag);
    hipLaunchKernelGGL(march_kernel, dim3((n + 255) / 256), dim3(256), 0, stream,
                       rays_o, dirs, occ, flag, eff, n, step, max_steps);

    long long total = (long long)n * NPTS;
    hipLaunchKernelGGL(sample_kernel, dim3((int)((total + 255) / 256)), dim3(256), 0, stream,
                       rays_o, dirs, t_rand, eff, out_pts, out_z, n);
}